// Round 1
// baseline (116.227 us; speedup 1.0000x reference)
//
#include <hip/hip_runtime.h>
#include <stdint.h>

typedef unsigned short u16;
typedef __attribute__((ext_vector_type(4))) float f32x4;
typedef __attribute__((ext_vector_type(8))) short short8;
typedef __attribute__((ext_vector_type(8))) unsigned short u16x8;

static constexpr int Bq = 8192;     // batch
static constexpr int Dq = 1024;     // feature dim (K)
static constexpr int Eq = 32;       // experts
static constexpr int Aq = 128;      // actions
static constexpr int NSTRAT = 4096; // E*A strat columns
static constexpr int NCOLS = 4224;  // 4096 strat + 32 logit + 96 pad = 33*128

__device__ inline u16 f32_to_bf16_rne(float f) {
    uint32_t u = __float_as_uint(f);
    uint32_t r = 0x7fffu + ((u >> 16) & 1u);
    return (u16)((u + r) >> 16);
}
__device__ inline float bf16_to_f32(u16 h) {
    return __uint_as_float(((uint32_t)h) << 16);
}

// ---------------- convert x: f32 -> bf16 ----------------
__global__ __launch_bounds__(256) void cvt_x_kernel(const float* __restrict__ src,
                                                    u16* __restrict__ dst) {
    size_t i = ((size_t)blockIdx.x * 256 + threadIdx.x) * 8;
    f32x4 a = *(const f32x4*)(src + i);
    f32x4 b = *(const f32x4*)(src + i + 4);
    u16x8 o;
    o[0] = f32_to_bf16_rne(a[0]); o[1] = f32_to_bf16_rne(a[1]);
    o[2] = f32_to_bf16_rne(a[2]); o[3] = f32_to_bf16_rne(a[3]);
    o[4] = f32_to_bf16_rne(b[0]); o[5] = f32_to_bf16_rne(b[1]);
    o[6] = f32_to_bf16_rne(b[2]); o[7] = f32_to_bf16_rne(b[3]);
    *(u16x8*)(dst + i) = o;
}

// ---------------- build Wb[4224][1024] bf16: W_strat rows 0..4095, W_att rows 4096..4127, zeros after
__global__ __launch_bounds__(256) void cvt_w_kernel(const float* __restrict__ W_strat,
                                                    const float* __restrict__ W_att,
                                                    u16* __restrict__ dst) {
    size_t i = ((size_t)blockIdx.x * 256 + threadIdx.x) * 8;
    int row = (int)(i >> 10);
    int col = (int)(i & 1023);
    u16x8 o;
    if (row < NSTRAT) {
        const float* s = W_strat + i;
        f32x4 a = *(const f32x4*)(s);
        f32x4 b = *(const f32x4*)(s + 4);
        o[0] = f32_to_bf16_rne(a[0]); o[1] = f32_to_bf16_rne(a[1]);
        o[2] = f32_to_bf16_rne(a[2]); o[3] = f32_to_bf16_rne(a[3]);
        o[4] = f32_to_bf16_rne(b[0]); o[5] = f32_to_bf16_rne(b[1]);
        o[6] = f32_to_bf16_rne(b[2]); o[7] = f32_to_bf16_rne(b[3]);
    } else if (row < NSTRAT + Eq) {
        const float* s = W_att + ((size_t)(row - NSTRAT) << 10) + col;
        f32x4 a = *(const f32x4*)(s);
        f32x4 b = *(const f32x4*)(s + 4);
        o[0] = f32_to_bf16_rne(a[0]); o[1] = f32_to_bf16_rne(a[1]);
        o[2] = f32_to_bf16_rne(a[2]); o[3] = f32_to_bf16_rne(a[3]);
        o[4] = f32_to_bf16_rne(b[0]); o[5] = f32_to_bf16_rne(b[1]);
        o[6] = f32_to_bf16_rne(b[2]); o[7] = f32_to_bf16_rne(b[3]);
    } else {
        o = (u16x8)0;
    }
    *(u16x8*)(dst + i) = o;
}

// ---------------- main GEMM: S[8192][4224] = xb[8192][1024] @ Wb[4224][1024]^T (bf16, f32 acc)
#define BM 128
#define BN 128
#define BK 32

__device__ inline void gload_lds16(const u16* g, u16* l) {
    __builtin_amdgcn_global_load_lds(
        (const __attribute__((address_space(1))) void*)g,
        (__attribute__((address_space(3))) void*)l, 16, 0, 0);
}

__global__ __launch_bounds__(256) void gemm_kernel(const u16* __restrict__ Abuf,
                                                   const u16* __restrict__ Bbuf,
                                                   u16* __restrict__ S) {
    __shared__ __align__(16) u16 As[BM * BK];
    __shared__ __align__(16) u16 Bs[BN * BK];
    const int m0 = blockIdx.x * BM;
    const int n0 = blockIdx.y * BN;
    const int tid = threadIdx.x;
    const int wave = tid >> 6;
    const int lane = tid & 63;
    const int wr = wave >> 1, wc = wave & 1;   // 2x2 waves, each 64x64
    const int fr = lane & 15;
    const int fq = lane >> 4;

    f32x4 acc[4][4] = {};

    for (int kk = 0; kk < Dq; kk += BK) {
        if (kk > 0) __syncthreads();   // LDS reuse: prior compute must finish
#pragma unroll
        for (int i = 0; i < 2; ++i) {
            int chunk = i * 256 + tid;       // 0..511, 8 elems each
            int r = chunk >> 2;              // row 0..127
            int c = (chunk & 3) * 8;         // col
            gload_lds16(Abuf + (size_t)(m0 + r) * Dq + kk + c, As + chunk * 8);
            gload_lds16(Bbuf + (size_t)(n0 + r) * Dq + kk + c, Bs + chunk * 8);
        }
        __syncthreads();                     // compiler drains vmcnt before barrier

        short8 a[4], b[4];
#pragma unroll
        for (int i = 0; i < 4; ++i)
            a[i] = *(const short8*)(As + (wr * 64 + i * 16 + fr) * BK + fq * 8);
#pragma unroll
        for (int j = 0; j < 4; ++j)
            b[j] = *(const short8*)(Bs + (wc * 64 + j * 16 + fr) * BK + fq * 8);
#pragma unroll
        for (int i = 0; i < 4; ++i)
#pragma unroll
            for (int j = 0; j < 4; ++j)
                acc[i][j] = __builtin_amdgcn_mfma_f32_16x16x32_bf16(a[i], b[j], acc[i][j], 0, 0, 0);
    }

    // epilogue: C/D layout col=lane&15, row=(lane>>4)*4+q  [m89-verified]
#pragma unroll
    for (int i = 0; i < 4; ++i)
#pragma unroll
        for (int j = 0; j < 4; ++j)
#pragma unroll
            for (int q = 0; q < 4; ++q) {
                int row = m0 + wr * 64 + i * 16 + fq * 4 + q;
                int col = n0 + wc * 64 + j * 16 + fr;
                S[(size_t)row * NCOLS + col] = f32_to_bf16_rne(acc[i][j][q]);
            }
}

// ---------------- gating weights: gumbel softmax over E=32 ----------------
__global__ __launch_bounds__(256) void weights_kernel(const u16* __restrict__ S,
                                                      const float* __restrict__ gu,
                                                      const float* __restrict__ b_att,
                                                      const float* __restrict__ abias,
                                                      float* __restrict__ w) {
    int idx = blockIdx.x * 256 + threadIdx.x;   // 0 .. B*32-1
    int b = idx >> 5;
    int e = idx & 31;
    float lg = bf16_to_f32(S[(size_t)b * NCOLS + NSTRAT + e]);
    float u = gu[idx];
    // accurate logf: hw __logf near u->1 loses all precision in -log(u)
    float g = -logf(-logf(u + 1e-10f) + 1e-10f);
    float z = lg + b_att[e] + abias[e] + g;     // TAU = 1
    float m = z;
#pragma unroll
    for (int s = 1; s < 32; s <<= 1) m = fmaxf(m, __shfl_xor(m, s, 32));
    float p = __expf(z - m);
    float sum = p;
#pragma unroll
    for (int s = 1; s < 32; s <<= 1) sum += __shfl_xor(sum, s, 32);
    w[idx] = p / sum;
}

// ---------------- combine: out[b,a] = sum_e w[b,e]*(S[b,e*128+a] + b_strat[e,a])
__global__ __launch_bounds__(256) void combine_kernel(const u16* __restrict__ S,
                                                      const float* __restrict__ w,
                                                      const float* __restrict__ b_strat,
                                                      float* __restrict__ out) {
    int b = blockIdx.x * 2 + (threadIdx.x >> 7);
    int a = threadIdx.x & 127;
    const u16* Srow = S + (size_t)b * NCOLS;
    const float* wrow = w + (size_t)b * 32;
    float acc = 0.f;
#pragma unroll
    for (int e = 0; e < 32; ++e) {
        acc += wrow[e] * (bf16_to_f32(Srow[e * 128 + a]) + b_strat[e * 128 + a]);
    }
    out[(size_t)b * 128 + a] = acc;
}

extern "C" void kernel_launch(void* const* d_in, const int* in_sizes, int n_in,
                              void* d_out, int out_size, void* d_ws, size_t ws_size,
                              hipStream_t stream) {
    const float* x       = (const float*)d_in[0];
    const float* W_att   = (const float*)d_in[1];
    const float* b_att   = (const float*)d_in[2];
    const float* abias   = (const float*)d_in[3];
    const float* W_strat = (const float*)d_in[4];
    const float* b_strat = (const float*)d_in[5];
    const float* gu      = (const float*)d_in[6];
    float* out = (float*)d_out;

    // workspace layout (bytes): xb 16.78M | Wb 8.65M | S 69.2M | w 1.05M  (~95.7MB)
    u16* xb = (u16*)d_ws;                          // [8192][1024]
    u16* Wb = xb + (size_t)Bq * Dq;                // [4224][1024]
    u16* S  = Wb + (size_t)NCOLS * Dq;             // [8192][4224]
    float* w = (float*)(S + (size_t)Bq * NCOLS);   // [8192][32]

    // 1. converts
    cvt_x_kernel<<<(Bq * Dq) / (256 * 8), 256, 0, stream>>>(x, xb);
    cvt_w_kernel<<<(NCOLS * Dq) / (256 * 8), 256, 0, stream>>>(W_strat, W_att, Wb);

    // 2. big GEMM (includes gating logits in cols 4096..4127)
    dim3 ggrid(Bq / BM, NCOLS / BN);
    gemm_kernel<<<ggrid, 256, 0, stream>>>(xb, Wb, S);

    // 3. gumbel-softmax weights
    weights_kernel<<<(Bq * Eq) / 256, 256, 0, stream>>>(S, gu, b_att, abias, w);

    // 4. weighted combine
    combine_kernel<<<Bq / 2, 256, 0, stream>>>(S, w, b_strat, out);
}

// Round 2
// 108.700 us; speedup vs baseline: 1.0692x; 1.0692x over previous
//
#include <hip/hip_runtime.h>
#include <stdint.h>

typedef unsigned short u16;
typedef __attribute__((ext_vector_type(4))) float f32x4;
typedef __attribute__((ext_vector_type(8))) short short8;
typedef __attribute__((ext_vector_type(8))) unsigned short u16x8;

static constexpr int Bq = 8192;     // batch
static constexpr int Dq = 1024;     // feature dim (K)
static constexpr int Eq = 32;       // experts
static constexpr int Aq = 128;      // actions
static constexpr int NSTRAT = 4096; // E*A strat columns = GEMM N

__device__ inline u16 f32_to_bf16_rne(float f) {
    uint32_t u = __float_as_uint(f);
    uint32_t r = 0x7fffu + ((u >> 16) & 1u);
    return (u16)((u + r) >> 16);
}
__device__ inline float bf16_to_f32(u16 h) {
    return __uint_as_float(((uint32_t)h) << 16);
}
__device__ inline void gload_lds16(const u16* g, u16* l) {
    __builtin_amdgcn_global_load_lds(
        (const __attribute__((address_space(1))) void*)g,
        (__attribute__((address_space(3))) void*)l, 16, 0, 0);
}

// ---------------- convert x: f32 -> bf16 ----------------
__global__ __launch_bounds__(256) void cvt_x_kernel(const float* __restrict__ src,
                                                    u16* __restrict__ dst) {
    size_t i = ((size_t)blockIdx.x * 256 + threadIdx.x) * 8;
    f32x4 a = *(const f32x4*)(src + i);
    f32x4 b = *(const f32x4*)(src + i + 4);
    u16x8 o;
    o[0] = f32_to_bf16_rne(a[0]); o[1] = f32_to_bf16_rne(a[1]);
    o[2] = f32_to_bf16_rne(a[2]); o[3] = f32_to_bf16_rne(a[3]);
    o[4] = f32_to_bf16_rne(b[0]); o[5] = f32_to_bf16_rne(b[1]);
    o[6] = f32_to_bf16_rne(b[2]); o[7] = f32_to_bf16_rne(b[3]);
    *(u16x8*)(dst + i) = o;
}

// ---------------- convert W_strat -> bf16 [4096][1024] ----------------
__global__ __launch_bounds__(256) void cvt_w_kernel(const float* __restrict__ src,
                                                    u16* __restrict__ dst) {
    size_t i = ((size_t)blockIdx.x * 256 + threadIdx.x) * 8;
    f32x4 a = *(const f32x4*)(src + i);
    f32x4 b = *(const f32x4*)(src + i + 4);
    u16x8 o;
    o[0] = f32_to_bf16_rne(a[0]); o[1] = f32_to_bf16_rne(a[1]);
    o[2] = f32_to_bf16_rne(a[2]); o[3] = f32_to_bf16_rne(a[3]);
    o[4] = f32_to_bf16_rne(b[0]); o[5] = f32_to_bf16_rne(b[1]);
    o[6] = f32_to_bf16_rne(b[2]); o[7] = f32_to_bf16_rne(b[3]);
    *(u16x8*)(dst + i) = o;
}

// ================= 256x256 8-phase GEMM =================
// S[8192][4096] = xb[8192][1024] @ Wb[4096][1024]^T, bf16 in / f32 acc / bf16 out
#define FBAR do { asm volatile("" ::: "memory"); __builtin_amdgcn_s_barrier(); asm volatile("" ::: "memory"); } while (0)
#define LGKM0 asm volatile("s_waitcnt lgkmcnt(0)" ::: "memory")
#define VMCNT(n) asm volatile("s_waitcnt vmcnt(" #n ")" ::: "memory")
#define SB __builtin_amdgcn_sched_barrier(0)
#define PRIO1 __builtin_amdgcn_s_setprio(1)
#define PRIO0 __builtin_amdgcn_s_setprio(0)
#define MF(a, b, c) __builtin_amdgcn_mfma_f32_16x16x32_bf16(a, b, c, 0, 0, 0)

// LDS: 2 buffers (K-tile parity) x 4 regions (A-h0, A-h1, B-h0, B-h1) x 16KB.
// Swizzle: within a region (row stride 128B), byte ^= (row&7)<<4 (elem ^= (row&7)<<3).
// Staged linearly via pre-swizzled global source (rule #21).

#define STAGE_A(buf, h, kt) do { \
    gload_lds16(agA + (size_t)((h)*128) * 1024 + (size_t)(kt) * 64, (u16*)&lds[buf][h][tid * 8]); \
    gload_lds16(agA + (size_t)((h)*128 + 64) * 1024 + (size_t)(kt) * 64, (u16*)&lds[buf][h][4096 + tid * 8]); \
} while (0)
#define STAGE_B(buf, h, kt) do { \
    gload_lds16(agB + (size_t)((h)*128) * 1024 + (size_t)(kt) * 64, (u16*)&lds[buf][2 + (h)][tid * 8]); \
    gload_lds16(agB + (size_t)((h)*128 + 64) * 1024 + (size_t)(kt) * 64, (u16*)&lds[buf][2 + (h)][4096 + tid * 8]); \
} while (0)

#define LDA8(DST, ABASE, mq) do { \
    DST[0] = *(const short8*)((ABASE) + (mq)*4096 + 0*1024 + aoff0); \
    DST[1] = *(const short8*)((ABASE) + (mq)*4096 + 0*1024 + aoff1); \
    DST[2] = *(const short8*)((ABASE) + (mq)*4096 + 1*1024 + aoff0); \
    DST[3] = *(const short8*)((ABASE) + (mq)*4096 + 1*1024 + aoff1); \
    DST[4] = *(const short8*)((ABASE) + (mq)*4096 + 2*1024 + aoff0); \
    DST[5] = *(const short8*)((ABASE) + (mq)*4096 + 2*1024 + aoff1); \
    DST[6] = *(const short8*)((ABASE) + (mq)*4096 + 3*1024 + aoff0); \
    DST[7] = *(const short8*)((ABASE) + (mq)*4096 + 3*1024 + aoff1); \
} while (0)
#define LDB4(DST, BBASE, nq) do { \
    DST[0] = *(const short8*)((BBASE) + (nq)*2048 + 0*1024 + boff0); \
    DST[1] = *(const short8*)((BBASE) + (nq)*2048 + 0*1024 + boff1); \
    DST[2] = *(const short8*)((BBASE) + (nq)*2048 + 1*1024 + boff0); \
    DST[3] = *(const short8*)((BBASE) + (nq)*2048 + 1*1024 + boff1); \
} while (0)

#define QUAD(mq, nq, AS, BS) do { \
    acc[(mq)*4+0][(nq)*2+0] = MF(AS[0], BS[0], acc[(mq)*4+0][(nq)*2+0]); \
    acc[(mq)*4+0][(nq)*2+1] = MF(AS[0], BS[2], acc[(mq)*4+0][(nq)*2+1]); \
    acc[(mq)*4+1][(nq)*2+0] = MF(AS[2], BS[0], acc[(mq)*4+1][(nq)*2+0]); \
    acc[(mq)*4+1][(nq)*2+1] = MF(AS[2], BS[2], acc[(mq)*4+1][(nq)*2+1]); \
    acc[(mq)*4+2][(nq)*2+0] = MF(AS[4], BS[0], acc[(mq)*4+2][(nq)*2+0]); \
    acc[(mq)*4+2][(nq)*2+1] = MF(AS[4], BS[2], acc[(mq)*4+2][(nq)*2+1]); \
    acc[(mq)*4+3][(nq)*2+0] = MF(AS[6], BS[0], acc[(mq)*4+3][(nq)*2+0]); \
    acc[(mq)*4+3][(nq)*2+1] = MF(AS[6], BS[2], acc[(mq)*4+3][(nq)*2+1]); \
    acc[(mq)*4+0][(nq)*2+0] = MF(AS[1], BS[1], acc[(mq)*4+0][(nq)*2+0]); \
    acc[(mq)*4+0][(nq)*2+1] = MF(AS[1], BS[3], acc[(mq)*4+0][(nq)*2+1]); \
    acc[(mq)*4+1][(nq)*2+0] = MF(AS[3], BS[1], acc[(mq)*4+1][(nq)*2+0]); \
    acc[(mq)*4+1][(nq)*2+1] = MF(AS[3], BS[3], acc[(mq)*4+1][(nq)*2+1]); \
    acc[(mq)*4+2][(nq)*2+0] = MF(AS[5], BS[1], acc[(mq)*4+2][(nq)*2+0]); \
    acc[(mq)*4+2][(nq)*2+1] = MF(AS[5], BS[3], acc[(mq)*4+2][(nq)*2+1]); \
    acc[(mq)*4+3][(nq)*2+0] = MF(AS[7], BS[1], acc[(mq)*4+3][(nq)*2+0]); \
    acc[(mq)*4+3][(nq)*2+1] = MF(AS[7], BS[3], acc[(mq)*4+3][(nq)*2+1]); \
} while (0)

// One iteration = 2 K-tiles (t even -> buf0, t+1 -> buf1), 8 phases.
// Reads: ph1 B(t)n0 | ph2 B(t)n1 | ph3 A(t)m1 | ph4 A(t+1)m0 | ph5 B(t+1)n0
//        ph6 B(t+1)n1 | ph7 A(t+1)m1 | ph8 A(t+2)m0   (A(t)m0 carried from prev ph8)
// Stages: ph1 A0(t+1) ph2 A1(t+1) ph3 B0(t+2) ph4 B1(t+2) ph5 A0(t+2) ph6 A1(t+2)
//         ph7 B0(t+3) ph8 B1(t+3)
// vmcnt(2) before trailing barrier of ph3 (guards buf1 tile t+1) and ph7 (guards buf0 tile t+2).
#define GITER(t, TAIL) do { \
    /* ph1 */ \
    LDB4(Bs0, Bbase0, 0); \
    STAGE_A(1, 0, (t) + 1); \
    SB; FBAR; LGKM0; SB; \
    PRIO1; QUAD(0, 0, As0, Bs0); PRIO0; SB; FBAR; \
    /* ph2 */ \
    LDB4(Bs1, Bbase0, 1); \
    STAGE_A(1, 1, (t) + 1); \
    SB; FBAR; LGKM0; SB; \
    PRIO1; QUAD(0, 1, As0, Bs1); PRIO0; SB; FBAR; \
    /* ph3 */ \
    LDA8(As1, Abase0, 1); \
    if (!(TAIL)) STAGE_B(0, 0, (t) + 2); \
    SB; FBAR; LGKM0; SB; \
    PRIO1; QUAD(1, 1, As1, Bs1); PRIO0; SB; \
    if (TAIL) { VMCNT(0); } else { VMCNT(2); } \
    FBAR; \
    /* ph4 */ \
    LDA8(As0, Abase1, 0); \
    if (!(TAIL)) STAGE_B(0, 1, (t) + 2); \
    SB; FBAR; LGKM0; SB; \
    PRIO1; QUAD(1, 0, As1, Bs0); PRIO0; SB; FBAR; \
    /* ph5 */ \
    LDB4(Bs0, Bbase1, 0); \
    if (!(TAIL)) STAGE_A(0, 0, (t) + 2); \
    SB; FBAR; LGKM0; SB; \
    PRIO1; QUAD(0, 0, As0, Bs0); PRIO0; SB; FBAR; \
    /* ph6 */ \
    LDB4(Bs1, Bbase1, 1); \
    if (!(TAIL)) STAGE_A(0, 1, (t) + 2); \
    SB; FBAR; LGKM0; SB; \
    PRIO1; QUAD(0, 1, As0, Bs1); PRIO0; SB; FBAR; \
    /* ph7 */ \
    LDA8(As1, Abase1, 1); \
    if (!(TAIL)) STAGE_B(1, 0, (t) + 3); \
    SB; FBAR; LGKM0; SB; \
    PRIO1; QUAD(1, 1, As1, Bs1); PRIO0; SB; \
    if (!(TAIL)) { VMCNT(2); } \
    FBAR; \
    /* ph8 */ \
    if (!(TAIL)) { LDA8(As0, Abase0, 0); STAGE_B(1, 1, (t) + 3); } \
    SB; FBAR; LGKM0; SB; \
    PRIO1; QUAD(1, 0, As1, Bs0); PRIO0; SB; FBAR; \
} while (0)

__global__ __launch_bounds__(512, 2) void gemm256(const u16* __restrict__ Abuf,
                                                  const u16* __restrict__ Bbuf,
                                                  u16* __restrict__ S) {
    __shared__ __align__(16) u16 lds[2][4][8192]; // 128 KiB

    const int tid = threadIdx.x;
    const int lane = tid & 63;
    const int wv = tid >> 6;
    const int wr = wv >> 2;      // 0..1 (M)
    const int wc = wv & 3;       // 0..3 (N)
    const int fr = lane & 15;
    const int fq = lane >> 4;

    // XCD-aware bijective swizzle (512 % 8 == 0)
    const int bid = blockIdx.x;
    const int swz = (bid & 7) * 64 + (bid >> 3);
    const int m0 = (swz >> 4) * 256;
    const int n0 = (swz & 15) * 256;

    // staging: per-thread linear LDS slot -> pre-swizzled global source
    const int s_r = tid >> 3;                               // row in half (0..63), +64 for 2nd load
    const int s_c = ((tid & 7) * 8) ^ ((s_r & 7) << 3);     // elem col, inverse-swizzled
    const u16* agA = Abuf + (size_t)(m0 + s_r) * 1024 + s_c;
    const u16* agB = Bbuf + (size_t)(n0 + s_r) * 1024 + s_c;

    // frag-read offsets (u16 units) within a 128x64 region, row stride 64 u16
    const int aoff0 = fr * 64 + ((fq ^ (fr & 7)) * 8);
    const int aoff1 = fr * 64 + (((fq + 4) ^ (fr & 7)) * 8);
    const int bof = (wc & 1) * 4096;
    const int boff0 = bof + aoff0;
    const int boff1 = bof + aoff1;

    const u16* Abase0 = (const u16*)&lds[0][wr][0];
    const u16* Abase1 = (const u16*)&lds[1][wr][0];
    const u16* Bbase0 = (const u16*)&lds[0][2 + (wc >> 1)][0];
    const u16* Bbase1 = (const u16*)&lds[1][2 + (wc >> 1)][0];

    f32x4 acc[8][4] = {};
    short8 As0[8], As1[8], Bs0[4], Bs1[4];

    // prologue: kt0 full into buf0, B(kt1) into buf1, then force kt0, pre-read A(kt0)m0
    STAGE_A(0, 0, 0); STAGE_A(0, 1, 0); STAGE_B(0, 0, 0); STAGE_B(0, 1, 0);
    STAGE_B(1, 0, 1); STAGE_B(1, 1, 1);
    SB; VMCNT(4); FBAR;
    LDA8(As0, Abase0, 0);

#pragma unroll 1
    for (int t = 0; t < 14; t += 2) { GITER(t, 0); }
    GITER(14, 1);

    // epilogue: C layout col = lane&15, row = (lane>>4)*4 + q (m89-verified)
    const int crow = m0 + wr * 128 + fq * 4;
    const int ccol = n0 + wc * 64 + fr;
#pragma unroll
    for (int im = 0; im < 8; ++im)
#pragma unroll
        for (int jn = 0; jn < 4; ++jn)
#pragma unroll
            for (int q = 0; q < 4; ++q)
                S[(size_t)(crow + im * 16 + q) * NSTRAT + ccol + jn * 16] =
                    f32_to_bf16_rne(acc[im][jn][q]);
}

// ============ gating: logits GEMV (MFMA) + gumbel-softmax, fused -> w ============
// grid 64 blocks x 512 thr (8 waves x 16 rows), W_att staged bf16 in LDS.
__global__ __launch_bounds__(512) void logits_kernel(const u16* __restrict__ xb,
                                                     const float* __restrict__ W_att,
                                                     const float* __restrict__ b_att,
                                                     const float* __restrict__ abias,
                                                     const float* __restrict__ gu,
                                                     float* __restrict__ w) {
    __shared__ __align__(16) u16 Wa[32][1032]; // pad 8 u16: row stride 2064 B (16B-aligned, banks spread)

    const int tid = threadIdx.x;
    const int lane = tid & 63;
    const int wv = tid >> 6;
    const int fr = lane & 15;
    const int fq = lane >> 4;
    const int m0 = blockIdx.x * 128;

    // stage W_att f32 -> bf16 LDS
    {
        const int row = tid >> 4;            // 0..31
        const int col0 = (tid & 15) * 64;
        const float* src = W_att + (size_t)row * 1024 + col0;
        u16* dst = &Wa[row][col0];
#pragma unroll
        for (int it = 0; it < 8; ++it) {
            f32x4 a = *(const f32x4*)(src + it * 8);
            f32x4 b = *(const f32x4*)(src + it * 8 + 4);
            u16x8 o;
            o[0] = f32_to_bf16_rne(a[0]); o[1] = f32_to_bf16_rne(a[1]);
            o[2] = f32_to_bf16_rne(a[2]); o[3] = f32_to_bf16_rne(a[3]);
            o[4] = f32_to_bf16_rne(b[0]); o[5] = f32_to_bf16_rne(b[1]);
            o[6] = f32_to_bf16_rne(b[2]); o[7] = f32_to_bf16_rne(b[3]);
            *(u16x8*)(dst + it * 8) = o;
        }
    }
    __syncthreads();

    f32x4 acc0 = {}, acc1 = {};
    const u16* xrow = xb + (size_t)(m0 + wv * 16 + fr) * 1024 + fq * 8;
#pragma unroll 4
    for (int k0 = 0; k0 < 1024; k0 += 32) {
        short8 a0 = *(const short8*)(xrow + k0);
        short8 b0 = *(const short8*)(&Wa[fr][k0 + fq * 8]);
        short8 b1 = *(const short8*)(&Wa[16 + fr][k0 + fq * 8]);
        acc0 = MF(a0, b0, acc0);
        acc1 = MF(a0, b1, acc1);
    }

    // fused gumbel-softmax over E=32 (two jn halves), per output row
    const float bba0 = b_att[fr] + abias[fr];
    const float bba1 = b_att[16 + fr] + abias[16 + fr];
#pragma unroll
    for (int q = 0; q < 4; ++q) {
        const int row = m0 + wv * 16 + fq * 4 + q;
        float u0 = gu[(size_t)row * 32 + fr];
        float u1 = gu[(size_t)row * 32 + 16 + fr];
        // accurate logf: hw __logf near u->1 loses all precision in -log(u)
        float g0 = -logf(-logf(u0 + 1e-10f) + 1e-10f);
        float g1 = -logf(-logf(u1 + 1e-10f) + 1e-10f);
        float z0 = acc0[q] + bba0 + g0;
        float z1 = acc1[q] + bba1 + g1;
        float mx = fmaxf(z0, z1);
#pragma unroll
        for (int s = 1; s < 16; s <<= 1) mx = fmaxf(mx, __shfl_xor(mx, s));
        float p0 = __expf(z0 - mx);
        float p1 = __expf(z1 - mx);
        float sm = p0 + p1;
#pragma unroll
        for (int s = 1; s < 16; s <<= 1) sm += __shfl_xor(sm, s);
        float inv = 1.0f / sm;
        w[(size_t)row * 32 + fr] = p0 * inv;
        w[(size_t)row * 32 + 16 + fr] = p1 * inv;
    }
}

// ---------------- combine: out[b,a] = sum_e w[b,e]*(S[b,e*128+a] + b_strat[e,a])
__global__ __launch_bounds__(256) void combine_kernel(const u16* __restrict__ S,
                                                      const float* __restrict__ w,
                                                      const float* __restrict__ b_strat,
                                                      float* __restrict__ out) {
    int b = blockIdx.x * 2 + (threadIdx.x >> 7);
    int a = threadIdx.x & 127;
    const u16* Srow = S + (size_t)b * NSTRAT;
    const float* wrow = w + (size_t)b * 32;
    float acc = 0.f;
#pragma unroll
    for (int e = 0; e < 32; ++e) {
        acc += wrow[e] * (bf16_to_f32(Srow[e * 128 + a]) + b_strat[e * 128 + a]);
    }
    out[(size_t)b * 128 + a] = acc;
}

extern "C" void kernel_launch(void* const* d_in, const int* in_sizes, int n_in,
                              void* d_out, int out_size, void* d_ws, size_t ws_size,
                              hipStream_t stream) {
    (void)in_sizes; (void)n_in; (void)out_size; (void)ws_size;
    const float* x       = (const float*)d_in[0];
    const float* W_att   = (const float*)d_in[1];
    const float* b_att   = (const float*)d_in[2];
    const float* abias   = (const float*)d_in[3];
    const float* W_strat = (const float*)d_in[4];
    const float* b_strat = (const float*)d_in[5];
    const float* gu      = (const float*)d_in[6];
    float* out = (float*)d_out;

    // ws layout: xb 16.78M | Wb 8.39M | S 67.11M | w 1.05M  (= 93.3 MB total)
    u16* xb = (u16*)d_ws;                          // [8192][1024]
    u16* Wb = xb + (size_t)Bq * Dq;                // [4096][1024]
    u16* S  = Wb + (size_t)NSTRAT * Dq;            // [8192][4096]
    float* w = (float*)(S + (size_t)Bq * NSTRAT);  // [8192][32]

    cvt_x_kernel<<<(Bq * Dq) / (256 * 8), 256, 0, stream>>>(x, xb);
    cvt_w_kernel<<<(NSTRAT * Dq) / (256 * 8), 256, 0, stream>>>(W_strat, Wb);

    logits_kernel<<<Bq / 128, 512, 0, stream>>>(xb, W_att, b_att, abias, gu, w);

    gemm256<<<512, 512, 0, stream>>>(xb, Wb, S);

    combine_kernel<<<Bq / 2, 256, 0, stream>>>(S, w, b_strat, out);
}